// Round 3
// baseline (127604.858 us; speedup 1.0000x reference)
//
#include <hip/hip_runtime.h>
#include <cstddef>

__device__ __forceinline__ float sigm(float x) { return 1.f / (1.f + __expf(-x)); }
__device__ __forceinline__ float tanh_(float x) { return 1.f - 2.f / (__expf(2.f * x) + 1.f); }

#define AGLD(p)    __hip_atomic_load((p),  __ATOMIC_RELAXED, __HIP_MEMORY_SCOPE_AGENT)
#define AGST(p, v) __hip_atomic_store((p), (v), __ATOMIC_RELAXED, __HIP_MEMORY_SCOPE_AGENT)
#define AGADD(p,v) __hip_atomic_fetch_add((p), (v), __ATOMIC_RELAXED, __HIP_MEMORY_SCOPE_AGENT)

// 16-wide fp32 dot block: accumulates into a0..a3 (declared by caller)
#define DOT16(wp, hp, kk) do { \
    float4 w0_ = *(const float4*)((wp) + (kk));      float4 x0_ = *(const float4*)((hp) + (kk)); \
    float4 w1_ = *(const float4*)((wp) + (kk) + 4);  float4 x1_ = *(const float4*)((hp) + (kk) + 4); \
    float4 w2_ = *(const float4*)((wp) + (kk) + 8);  float4 x2_ = *(const float4*)((hp) + (kk) + 8); \
    float4 w3_ = *(const float4*)((wp) + (kk) + 12); float4 x3_ = *(const float4*)((hp) + (kk) + 12); \
    a0 = fmaf(w0_.x, x0_.x, a0); a0 = fmaf(w0_.y, x0_.y, a0); a0 = fmaf(w0_.z, x0_.z, a0); a0 = fmaf(w0_.w, x0_.w, a0); \
    a1 = fmaf(w1_.x, x1_.x, a1); a1 = fmaf(w1_.y, x1_.y, a1); a1 = fmaf(w1_.z, x1_.z, a1); a1 = fmaf(w1_.w, x1_.w, a1); \
    a2 = fmaf(w2_.x, x2_.x, a2); a2 = fmaf(w2_.y, x2_.y, a2); a2 = fmaf(w2_.z, x2_.z, a2); a2 = fmaf(w2_.w, x2_.w, a2); \
    a3 = fmaf(w3_.x, x3_.x, a3); a3 = fmaf(w3_.y, x3_.y, a3); a3 = fmaf(w3_.z, x3_.z, a3); a3 = fmaf(w3_.w, x3_.w, a3); \
  } while (0)

// ---------------- K1: embed = relu(inputs @ W_e^T + b_e), layout [s][b][e] ----------------
__global__ __launch_bounds__(256) void k_embed(
    const float* __restrict__ inp, const float* __restrict__ We,
    const float* __restrict__ be, float* __restrict__ emb)
{
  __shared__ float sA[32 * 68];
  __shared__ float sW[32 * 132];
  const int tid = threadIdx.x;
  const int b  = blockIdx.x >> 4;
  const int s0 = (blockIdx.x & 15) << 6;
  float acc[4][8];
#pragma unroll
  for (int i = 0; i < 4; ++i)
#pragma unroll
    for (int j = 0; j < 8; ++j) acc[i][j] = 0.f;
  const int m4 = (tid & 15) << 2;
  const int e8 = (tid >> 4) << 3;
  const float* Ab = inp + ((size_t)(b << 10) + s0) * 1024;
  const int ms = tid >> 2, kq = tid & 3;
  const int es = tid >> 1, kq2 = tid & 1;
  for (int k0 = 0; k0 < 1024; k0 += 32) {
    __syncthreads();
    {
      const float* src = Ab + (size_t)ms * 1024 + k0 + (kq << 3);
      float4 v0 = *(const float4*)(src);
      float4 v1 = *(const float4*)(src + 4);
      int kb = kq << 3;
      sA[(kb+0)*68+ms] = v0.x; sA[(kb+1)*68+ms] = v0.y;
      sA[(kb+2)*68+ms] = v0.z; sA[(kb+3)*68+ms] = v0.w;
      sA[(kb+4)*68+ms] = v1.x; sA[(kb+5)*68+ms] = v1.y;
      sA[(kb+6)*68+ms] = v1.z; sA[(kb+7)*68+ms] = v1.w;
    }
    {
      const float* src = We + (size_t)es * 1024 + k0 + (kq2 << 4);
#pragma unroll
      for (int q = 0; q < 4; ++q) {
        float4 v = *(const float4*)(src + (q << 2));
        int kb = (kq2 << 4) + (q << 2);
        sW[(kb+0)*132+es] = v.x; sW[(kb+1)*132+es] = v.y;
        sW[(kb+2)*132+es] = v.z; sW[(kb+3)*132+es] = v.w;
      }
    }
    __syncthreads();
#pragma unroll 4
    for (int kk = 0; kk < 32; ++kk) {
      float4 a4 = *(const float4*)&sA[kk*68 + m4];
      float4 b0 = *(const float4*)&sW[kk*132 + e8];
      float4 b1 = *(const float4*)&sW[kk*132 + e8 + 4];
      float av[4] = {a4.x, a4.y, a4.z, a4.w};
      float bv[8] = {b0.x, b0.y, b0.z, b0.w, b1.x, b1.y, b1.z, b1.w};
#pragma unroll
      for (int i = 0; i < 4; ++i)
#pragma unroll
        for (int j = 0; j < 8; ++j) acc[i][j] = fmaf(av[i], bv[j], acc[i][j]);
    }
  }
#pragma unroll
  for (int i = 0; i < 4; ++i) {
    int s = s0 + m4 + i;
#pragma unroll
    for (int j = 0; j < 8; ++j) {
      float v = acc[i][j] + be[e8 + j];
      emb[((size_t)(s << 5) + b) * 128 + e8 + j] = v > 0.f ? v : 0.f;
    }
  }
}

// ---------------- K2: a = relu(embed @ Wa1^T + ba1) @ Wa2^T + ba2, layout [s*32+b][3] ----------------
__global__ __launch_bounds__(256) void k_attn(
    const float* __restrict__ emb, const float* __restrict__ Wa1,
    const float* __restrict__ ba1, const float* __restrict__ Wa2,
    const float* __restrict__ ba2, float* __restrict__ aw)
{
  __shared__ float sE[2 * 128];
  __shared__ float sH[2 * 128];
  const int tid = threadIdx.x;
  const int rs0 = blockIdx.x * 2;
  sE[tid] = emb[(size_t)rs0 * 128 + tid];
  __syncthreads();
  const int half = tid >> 7, j = tid & 127;
  const float* w = Wa1 + j * 128;
  const float* e = sE + half * 128;
  float a0 = 0.f, a1 = 0.f, a2 = 0.f, a3 = 0.f;
  for (int k = 0; k < 128; k += 16) DOT16(w, e, k);
  float h = (a0 + a1) + (a2 + a3) + ba1[j];
  sH[half * 128 + j] = h > 0.f ? h : 0.f;
  __syncthreads();
  if (tid < 6) {
    int hh = tid / 3, l = tid % 3;
    const float* w2 = Wa2 + l * 128;
    const float* hv = sH + hh * 128;
    float s = 0.f;
    for (int k = 0; k < 128; ++k) s = fmaf(w2[k], hv[k], s);
    aw[(size_t)(rs0 + hh) * 3 + l] = s + ba2[l];
  }
}

// ---------------- K2b: softmax over time (axis s) per (b, l), in-place ----------------
__global__ __launch_bounds__(256) void k_softmax(float* __restrict__ aw)
{
  __shared__ float red[256];
  const int b = blockIdx.x / 3, l = blockIdx.x % 3;
  const int tid = threadIdx.x;
  float v[4];
#pragma unroll
  for (int i = 0; i < 4; ++i) {
    int s = tid + i * 256;
    v[i] = aw[(size_t)(s * 32 + b) * 3 + l];
  }
  float mx = fmaxf(fmaxf(v[0], v[1]), fmaxf(v[2], v[3]));
  red[tid] = mx;
  __syncthreads();
  for (int off = 128; off > 0; off >>= 1) {
    if (tid < off) red[tid] = fmaxf(red[tid], red[tid + off]);
    __syncthreads();
  }
  mx = red[0];
  __syncthreads();
  float sm = 0.f;
#pragma unroll
  for (int i = 0; i < 4; ++i) sm += __expf(v[i] - mx);
  red[tid] = sm;
  __syncthreads();
  for (int off = 128; off > 0; off >>= 1) {
    if (tid < off) red[tid] += red[tid + off];
    __syncthreads();
  }
  float inv = 1.f / red[0];
#pragma unroll
  for (int i = 0; i < 4; ++i) {
    int s = tid + i * 256;
    aw[(size_t)(s * 32 + b) * 3 + l] = __expf(v[i] - mx) * inv;
  }
}

// ------- K_prep: repack Wih_d (516-stride) + bias sums + Wo1 transpose -------
__global__ __launch_bounds__(256) void k_prep(
    const float* __restrict__ Wih_d, const float* __restrict__ Wo1,
    const float* __restrict__ bih_e, const float* __restrict__ bhh_e,
    const float* __restrict__ bih_d, const float* __restrict__ bhh_d,
    float* __restrict__ wdpack, float* __restrict__ wo1t,
    float* __restrict__ bsum_e, float* __restrict__ bsum_d)
{
  const int row = blockIdx.x;           // 2048 rows
  const int tid = threadIdx.x;
  for (int q = tid; q < 516; q += 256) {
    float v = 0.f;
    if (q < 512)      v = Wih_d[(size_t)row * 513 + 1 + q];   // ctx part
    else if (q == 512) v = Wih_d[(size_t)row * 513];          // p coefficient
    wdpack[(size_t)row * 516 + q] = v;
  }
  if (row < 512) {   // wo1t[d][e] = Wo1[e][d]
    for (int e = tid; e < 512; e += 256)
      wo1t[(size_t)row * 512 + e] = Wo1[(size_t)e * 512 + row];
  }
  if (tid == 0) {
    bsum_e[row] = bih_e[row] + bhh_e[row];
    bsum_d[row] = bih_d[row] + bhh_d[row];
  }
}

// ---------------- K_init: initial states + barrier zero ----------------
__global__ __launch_bounds__(256) void k_init(
    const float* __restrict__ eh0, const float* __restrict__ dh0,
    const float* __restrict__ bo2,
    float* __restrict__ heb, float* __restrict__ hdb,
    float* __restrict__ out, unsigned* __restrict__ bar)
{
  const int i = blockIdx.x * 256 + threadIdx.x;   // 32768 threads
  if (i < 16384) {
    int k = i & 511;
    heb[16384 + i] = eh0[k];   // heb slot 1 holds h_e(-1)  (read at round 0)
    hdb[16384 + i] = dh0[k];   // hdb slot 1 holds h_d(-1)  (read at round 2)
  }
  out[i] = bo2[0];
  if (i < 1024) bar[i] = 0u;
}

// ---------------- group barrier: 64 wgs, two-level counter, UC atomics ----------------
__device__ __forceinline__ void groupbar(unsigned* gbar, int r, unsigned gen)
{
  __builtin_amdgcn_s_waitcnt(0);     // drain this wave's stores/atomics
  __syncthreads();
  if (threadIdx.x == 0) {
    asm volatile("" ::: "memory");
    unsigned old = AGADD(gbar + ((r >> 3) << 4), 1u);
    if (old == (gen << 3) - 1u)          // last of this sub-group of 8 wgs
      (void)AGADD(gbar + 128, 1u);
    while (AGLD(gbar + 128) < (gen << 3))
      __builtin_amdgcn_s_sleep(1);
    asm volatile("" ::: "memory");
  }
  __syncthreads();
}

// ---------------- K_persist: one barrier per round, skewed pipeline ----------------
// wg = (g = blockIdx>>6, r = blockIdx&63). Group g owns batches [g*8,g*8+8); slice r owns
// h-dims [r*8,(r+1)*8) of BOTH LSTMs. Round i computes (all deps strictly prior-round):
//   enc(i)          from h_e(i-1) [heb slot (i-1)&1], emb(i)
//   p(i-3)          from qacc slot (i-3)&3   (accumulated in round i-1), redundant per wg
//   dec(i-2)        from ctx(i-2) [slot (i-2)&3], h_d(i-3) [slot (i-3)&1], p(i-3)
//   q-partial(i-2)  = Wo1[:,slice]·h_d_slice(i-2), atomicAdd into qacc slot (i-2)&3
// qacc slot j&3 is zeroed in round j (no other toucher of that slot in round j;
// zero->add->read each separated by >=1 barrier). NO spins anywhere: ONE barrier/round.
__global__ __launch_bounds__(256) void k_persist(
    const float* __restrict__ emb, const float* __restrict__ aw,
    const int* __restrict__ lens,
    const float* __restrict__ Wih_e, const float* __restrict__ Whh_e,
    const float* __restrict__ Whh_d, const float* __restrict__ wdpack,
    const float* __restrict__ bsum_e, const float* __restrict__ bsum_d,
    const float* __restrict__ ec0, const float* __restrict__ dc0,
    const float* __restrict__ wo1t, const float* __restrict__ bo1,
    const float* __restrict__ Wo2, const float* __restrict__ bo2,
    const float* __restrict__ maskp,
    float* __restrict__ heb, float* __restrict__ hdb,
    float* __restrict__ ctxb, float* __restrict__ qacc,
    float* __restrict__ out, unsigned* __restrict__ bar)
{
  __shared__ float sHe[8 * 516];   // h_e(i-1)
  __shared__ float sCtx[8 * 516];  // ctx(i-2)
  __shared__ float sHd[8 * 516];   // h_d(i-3)
  __shared__ float sEmb[8 * 132];
  __shared__ float sGe[256], sGd[256];
  __shared__ float sHdSl[64];      // fresh h_d(i-2) slice (8 dims x 8 batches)
  __shared__ float sP[8];          // p(i-3) per batch

  const int tid = threadIdx.x;
  const int g = blockIdx.x >> 6;        // batch group 0..3
  const int r = blockIdx.x & 63;        // row slice 0..63
  const int rr = tid >> 3;              // gate-row within slice 0..31
  const int bb = tid & 7;               // batch within group 0..7
  const int grow = ((rr >> 3) << 9) + (r << 3) + (rr & 7);
  const int gb8 = g << 3;

  unsigned* gbar = bar + g * 160;

  const float be_row = bsum_e[grow];
  const float bd_row = bsum_d[grow];
  const float bo2v = bo2[0];

  // cell-state registers: tid < 64 owns (dim = r*8 + tid>>3, batch = gb8 + (tid&7))
  float c_e = 0.f, c_d = 0.f, hm1 = 0.f, hm2 = 0.f;
  float pc0 = 0.f, pc1 = 0.f, pc2 = 0.f, pc3 = 0.f;
  int len_b = 0;
  if (tid < 64) {
    int dim = (r << 3) + (tid >> 3);
    c_e = ec0[dim];
    c_d = dc0[dim];
    len_b = lens[gb8 + (tid & 7)];
    pc0 = wdpack[(size_t)(0 * 512 + dim) * 516 + 512];
    pc1 = wdpack[(size_t)(1 * 512 + dim) * 516 + 512];
    pc2 = wdpack[(size_t)(2 * 512 + dim) * 516 + 512];
    pc3 = wdpack[(size_t)(3 * 512 + dim) * 516 + 512];
  }

  const float* whe = Whh_e + (size_t)grow * 512;
  const float* wie = Wih_e + (size_t)grow * 128;
  const float* whd = Whh_d + (size_t)grow * 512;
  const float* wdc = wdpack + (size_t)grow * 516;
  const float* hX  = sHe  + bb * 516;
  const float* hC  = sCtx + bb * 516;
  const float* hD  = sHd  + bb * 516;
  const float* hE  = sEmb + bb * 132;

  for (int i = 0; i < 1027; ++i) {
    const bool doEnc = (i < 1024);
    const bool doDec = (i >= 2) && (i < 1026);
    const bool doP   = (i >= 3);

    // ---- zero own 64 elems of qacc slot i&3 (reused by adds in round i+2) ----
    if (tid < 64)
      AGST(qacc + (size_t)(i & 3) * 16384 + (size_t)gb8 * 512 + (r << 6) + tid, 0.f);

    // ---- stage (register-capped blocks: max 32 live) ----
    {
      const float* hep = heb  + (size_t)((i + 1) & 1) * 16384 + (size_t)gb8 * 512;
      const float* cpp = ctxb + (size_t)((i + 2) & 3) * 16384 + (size_t)gb8 * 512;
      float v[16], u[16];
#pragma unroll
      for (int j = 0; j < 16; ++j) {
        v[j] = AGLD(hep + tid + j * 256);
        u[j] = AGLD(cpp + tid + j * 256);
      }
#pragma unroll
      for (int j = 0; j < 16; ++j) {
        int ii = tid + j * 256, bi = ii >> 9, kk = ii & 511;
        sHe [bi * 516 + kk] = v[j];
        sCtx[bi * 516 + kk] = u[j];
      }
      const float* hdp = hdb + (size_t)((i + 1) & 1) * 16384 + (size_t)gb8 * 512;
#pragma unroll
      for (int j = 0; j < 16; ++j) v[j] = AGLD(hdp + tid + j * 256);
#pragma unroll
      for (int j = 0; j < 16; ++j) {
        int ii = tid + j * 256, bi = ii >> 9, kk = ii & 511;
        sHd[bi * 516 + kk] = v[j];
      }
      float4 ev = {0.f, 0.f, 0.f, 0.f};
      if (doEnc)
        ev = *(const float4*)(emb + (size_t)(i * 32 + gb8 + (tid >> 5)) * 128 + ((tid & 31) << 2));
      *(float4*)(sEmb + (tid >> 5) * 132 + ((tid & 31) << 2)) = ev;
    }
    __syncthreads();

    // ---- issue q-loads for p(i-3): batch tid>>5, elems (tid&31)+32k (coalesced) ----
    float qv[16];
    if (doP) {
      const float* qp = qacc + (size_t)((i + 1) & 3) * 16384
                      + (size_t)(gb8 + (tid >> 5)) * 512 + (tid & 31);
#pragma unroll
      for (int k = 0; k < 16; ++k) qv[k] = AGLD(qp + (k << 5));
    }

    // ---- enc gates: full 640-dot per (row,batch) thread ----
    if (doEnc) {
      float a0 = 0.f, a1 = 0.f, a2 = 0.f, a3 = 0.f;
#pragma unroll 4
      for (int k = 0; k < 512; k += 16) DOT16(whe, hX, k);
#pragma unroll
      for (int k = 0; k < 128; k += 16) DOT16(wie, hE, k);
      sGe[(rr << 3) + bb] = (a0 + a1) + (a2 + a3) + be_row;
    }

    // ---- finish p(i-3) redundantly (32 lanes per batch) ----
    {
      float ps = 0.f;
      if (doP) {
        const int e0 = tid & 31;
#pragma unroll
        for (int k = 0; k < 16; ++k) {
          int e = e0 + (k << 5);
          float q = qv[k] + bo1[e];
          ps = fmaf(q > 0.f ? q : 0.f, Wo2[e], ps);
        }
      }
      ps += __shfl_down(ps, 16);
      ps += __shfl_down(ps, 8);
      ps += __shfl_down(ps, 4);
      ps += __shfl_down(ps, 2);
      ps += __shfl_down(ps, 1);
      if ((tid & 31) == 0) sP[tid >> 5] = doP ? (ps + bo2v) : 0.f;
    }

    // ---- dec gates (p-independent): ctx(i-2), h_d(i-3) ----
    if (doDec) {
      float a0 = 0.f, a1 = 0.f, a2 = 0.f, a3 = 0.f;
#pragma unroll 2
      for (int k = 0; k < 512; k += 16) { DOT16(whd, hD, k); DOT16(wdc, hC, k); }
      sGd[(rr << 3) + bb] = (a0 + a1) + (a2 + a3) + bd_row;
    }
    __syncthreads();

    // ---- cells (wave 0) ----
    if (tid < 64) {
      const int dim = (r << 3) + (tid >> 3);
      const int gb = gb8 + (tid & 7);
      if (doEnc) {
        float gi = sGe[tid], gf = sGe[64 + tid], gg = sGe[128 + tid], go = sGe[192 + tid];
        c_e = sigm(gf) * c_e + sigm(gi) * tanh_(gg);
        float h = sigm(go) * tanh_(c_e);
        AGST(&heb[(size_t)(i & 1) * 16384 + (size_t)gb * 512 + dim], h);
        float hmv = (i < len_b) ? h : 0.f;
        const float* at = aw + (size_t)(i * 32 + gb) * 3;
        float ctx = at[0] * hmv + at[1] * hm1 + at[2] * hm2;
        hm2 = hm1; hm1 = hmv;
        AGST(&ctxb[(size_t)(i & 3) * 16384 + (size_t)gb * 512 + dim], ctx);
      }
      if (doDec) {
        float p = sP[tid & 7];     // p(i-3) = p((i-2)-1)
        float gi = sGd[tid]       + pc0 * p;
        float gf = sGd[64 + tid]  + pc1 * p;
        float gg = sGd[128 + tid] + pc2 * p;
        float go = sGd[192 + tid] + pc3 * p;
        c_d = sigm(gf) * c_d + sigm(gi) * tanh_(gg);
        float h = sigm(go) * tanh_(c_d);
        AGST(&hdb[(size_t)(i & 1) * 16384 + (size_t)gb * 512 + dim], h);  // slot (i-2)&1
        sHdSl[((tid >> 3) << 3) + (tid & 7)] = h;
      }
    }
    // designated writer: wg r (<8) writes out for batch gb8+r
    if (r < 8 && doP && tid == 0)
      AGST(&out[(size_t)(gb8 + r) * 1024 + (i - 3)], sP[r]);
    __syncthreads();

    // ---- q-partial for h_d(i-2): qacc[slot (i-2)&3][b][e] += Wo1[e][slice]·h_slice ----
    if (doDec) {
      const int b = tid & 7, ec = tid >> 3;         // e-chunk: 16 elems
      float* qdst = qacc + (size_t)((i + 2) & 3) * 16384
                  + (size_t)(gb8 + b) * 512 + (ec << 4);
      float acc[16];
#pragma unroll
      for (int k = 0; k < 16; ++k) acc[k] = 0.f;
#pragma unroll
      for (int d = 0; d < 8; ++d) {
        float h = sHdSl[(d << 3) + b];
        const float* wv = wo1t + (size_t)((r << 3) + d) * 512 + (ec << 4);
#pragma unroll
        for (int k4 = 0; k4 < 4; ++k4) {
          float4 w4 = *(const float4*)(wv + (k4 << 2));
          acc[k4 * 4 + 0] = fmaf(w4.x, h, acc[k4 * 4 + 0]);
          acc[k4 * 4 + 1] = fmaf(w4.y, h, acc[k4 * 4 + 1]);
          acc[k4 * 4 + 2] = fmaf(w4.z, h, acc[k4 * 4 + 2]);
          acc[k4 * 4 + 3] = fmaf(w4.w, h, acc[k4 * 4 + 3]);
        }
      }
#pragma unroll
      for (int k = 0; k < 16; ++k) atomicAdd(qdst + k, acc[k]);
    }

    groupbar(gbar, r, (unsigned)(i + 1));
  }

  // ---- mask own chunk: 128 outputs per wg (all out-writes barrier-covered) ----
  if (tid < 128) {
    int idx = blockIdx.x * 128 + tid;
    float v = AGLD(&out[idx]);
    out[idx] = v * maskp[idx];
  }
}

extern "C" void kernel_launch(void* const* d_in, const int* in_sizes, int n_in,
                              void* d_out, int out_size, void* d_ws, size_t ws_size,
                              hipStream_t stream)
{
  const float* inp   = (const float*)d_in[0];
  const float* maskp = (const float*)d_in[1];
  const int*   lens  = (const int*)d_in[2];
  const float* We    = (const float*)d_in[3];
  const float* be    = (const float*)d_in[4];
  const float* Wa1   = (const float*)d_in[5];
  const float* ba1   = (const float*)d_in[6];
  const float* Wa2   = (const float*)d_in[7];
  const float* ba2   = (const float*)d_in[8];
  const float* Wih_e = (const float*)d_in[9];
  const float* Whh_e = (const float*)d_in[10];
  const float* bih_e = (const float*)d_in[11];
  const float* bhh_e = (const float*)d_in[12];
  const float* eh0   = (const float*)d_in[13];
  const float* ec0   = (const float*)d_in[14];
  const float* Wih_d = (const float*)d_in[15];
  const float* Whh_d = (const float*)d_in[16];
  const float* bih_d = (const float*)d_in[17];
  const float* bhh_d = (const float*)d_in[18];
  const float* dh0   = (const float*)d_in[19];
  const float* dc0   = (const float*)d_in[20];
  const float* Wo1   = (const float*)d_in[21];
  const float* bo1   = (const float*)d_in[22];
  const float* Wo2   = (const float*)d_in[23];
  const float* bo2   = (const float*)d_in[24];

  float* ws     = (float*)d_ws;
  float* emb    = ws;                     // 4,194,304
  float* aw     = emb + 4194304;          //    98,304
  float* heb    = aw + 98304;             //    32,768 (2 slots)
  float* hdb    = heb + 32768;            //    32,768 (2 slots)
  float* ctxb   = hdb + 32768;            //    65,536 (4 slots)
  float* qacc   = ctxb + 65536;           //    65,536 (4 slots x 32 b x 512)
  float* wdpack = qacc + 65536;           // 1,056,768 (2048 x 516)
  float* wo1t   = wdpack + 1056768;       //   262,144 (512 x 512, transposed Wo1)
  float* bsum_e = wo1t + 262144;          //     2,048
  float* bsum_d = bsum_e + 2048;          //     2,048
  unsigned* bar = (unsigned*)(bsum_d + 2048);  // 1,024 (4 groups x 160)
  float* outf = (float*)d_out;

  k_embed<<<512, 256, 0, stream>>>(inp, We, be, emb);
  k_attn<<<16384, 256, 0, stream>>>(emb, Wa1, ba1, Wa2, ba2, aw);
  k_softmax<<<96, 256, 0, stream>>>(aw);
  k_prep<<<2048, 256, 0, stream>>>(Wih_d, Wo1, bih_e, bhh_e, bih_d, bhh_d,
                                   wdpack, wo1t, bsum_e, bsum_d);
  k_init<<<128, 256, 0, stream>>>(eh0, dh0, bo2, heb, hdb, outf, bar);

  k_persist<<<256, 256, 0, stream>>>(
      emb, aw, lens,
      Wih_e, Whh_e, Whh_d, wdpack, bsum_e, bsum_d,
      ec0, dc0, wo1t, bo1, Wo2, bo2, maskp,
      heb, hdb, ctxb, qacc, outf, bar);
}

// Round 4
// 47200.879 us; speedup vs baseline: 2.7034x; 2.7034x over previous
//
#include <hip/hip_runtime.h>
#include <cstddef>

__device__ __forceinline__ float sigm(float x) { return 1.f / (1.f + __expf(-x)); }
__device__ __forceinline__ float tanh_(float x) { return 1.f - 2.f / (__expf(2.f * x) + 1.f); }

#define AGLD(p)    __hip_atomic_load((p),  __ATOMIC_RELAXED, __HIP_MEMORY_SCOPE_AGENT)
#define AGST(p, v) __hip_atomic_store((p), (v), __ATOMIC_RELAXED, __HIP_MEMORY_SCOPE_AGENT)
#define AGADD(p,v) __hip_atomic_fetch_add((p), (v), __ATOMIC_RELAXED, __HIP_MEMORY_SCOPE_AGENT)

// 16-wide fp32 dot block: accumulates into a0..a3 (declared by caller)
#define DOT16(wp, hp, kk) do { \
    float4 w0_ = *(const float4*)((wp) + (kk));      float4 x0_ = *(const float4*)((hp) + (kk)); \
    float4 w1_ = *(const float4*)((wp) + (kk) + 4);  float4 x1_ = *(const float4*)((hp) + (kk) + 4); \
    float4 w2_ = *(const float4*)((wp) + (kk) + 8);  float4 x2_ = *(const float4*)((hp) + (kk) + 8); \
    float4 w3_ = *(const float4*)((wp) + (kk) + 12); float4 x3_ = *(const float4*)((hp) + (kk) + 12); \
    a0 = fmaf(w0_.x, x0_.x, a0); a0 = fmaf(w0_.y, x0_.y, a0); a0 = fmaf(w0_.z, x0_.z, a0); a0 = fmaf(w0_.w, x0_.w, a0); \
    a1 = fmaf(w1_.x, x1_.x, a1); a1 = fmaf(w1_.y, x1_.y, a1); a1 = fmaf(w1_.z, x1_.z, a1); a1 = fmaf(w1_.w, x1_.w, a1); \
    a2 = fmaf(w2_.x, x2_.x, a2); a2 = fmaf(w2_.y, x2_.y, a2); a2 = fmaf(w2_.z, x2_.z, a2); a2 = fmaf(w2_.w, x2_.w, a2); \
    a3 = fmaf(w3_.x, x3_.x, a3); a3 = fmaf(w3_.y, x3_.y, a3); a3 = fmaf(w3_.z, x3_.z, a3); a3 = fmaf(w3_.w, x3_.w, a3); \
  } while (0)

// ---------------- K1: embed = relu(inputs @ W_e^T + b_e), layout [s][b][e] ----------------
__global__ __launch_bounds__(256) void k_embed(
    const float* __restrict__ inp, const float* __restrict__ We,
    const float* __restrict__ be, float* __restrict__ emb)
{
  __shared__ float sA[32 * 68];
  __shared__ float sW[32 * 132];
  const int tid = threadIdx.x;
  const int b  = blockIdx.x >> 4;
  const int s0 = (blockIdx.x & 15) << 6;
  float acc[4][8];
#pragma unroll
  for (int i = 0; i < 4; ++i)
#pragma unroll
    for (int j = 0; j < 8; ++j) acc[i][j] = 0.f;
  const int m4 = (tid & 15) << 2;
  const int e8 = (tid >> 4) << 3;
  const float* Ab = inp + ((size_t)(b << 10) + s0) * 1024;
  const int ms = tid >> 2, kq = tid & 3;
  const int es = tid >> 1, kq2 = tid & 1;
  for (int k0 = 0; k0 < 1024; k0 += 32) {
    __syncthreads();
    {
      const float* src = Ab + (size_t)ms * 1024 + k0 + (kq << 3);
      float4 v0 = *(const float4*)(src);
      float4 v1 = *(const float4*)(src + 4);
      int kb = kq << 3;
      sA[(kb+0)*68+ms] = v0.x; sA[(kb+1)*68+ms] = v0.y;
      sA[(kb+2)*68+ms] = v0.z; sA[(kb+3)*68+ms] = v0.w;
      sA[(kb+4)*68+ms] = v1.x; sA[(kb+5)*68+ms] = v1.y;
      sA[(kb+6)*68+ms] = v1.z; sA[(kb+7)*68+ms] = v1.w;
    }
    {
      const float* src = We + (size_t)es * 1024 + k0 + (kq2 << 4);
#pragma unroll
      for (int q = 0; q < 4; ++q) {
        float4 v = *(const float4*)(src + (q << 2));
        int kb = (kq2 << 4) + (q << 2);
        sW[(kb+0)*132+es] = v.x; sW[(kb+1)*132+es] = v.y;
        sW[(kb+2)*132+es] = v.z; sW[(kb+3)*132+es] = v.w;
      }
    }
    __syncthreads();
#pragma unroll 4
    for (int kk = 0; kk < 32; ++kk) {
      float4 a4 = *(const float4*)&sA[kk*68 + m4];
      float4 b0 = *(const float4*)&sW[kk*132 + e8];
      float4 b1 = *(const float4*)&sW[kk*132 + e8 + 4];
      float av[4] = {a4.x, a4.y, a4.z, a4.w};
      float bv[8] = {b0.x, b0.y, b0.z, b0.w, b1.x, b1.y, b1.z, b1.w};
#pragma unroll
      for (int i = 0; i < 4; ++i)
#pragma unroll
        for (int j = 0; j < 8; ++j) acc[i][j] = fmaf(av[i], bv[j], acc[i][j]);
    }
  }
#pragma unroll
  for (int i = 0; i < 4; ++i) {
    int s = s0 + m4 + i;
#pragma unroll
    for (int j = 0; j < 8; ++j) {
      float v = acc[i][j] + be[e8 + j];
      emb[((size_t)(s << 5) + b) * 128 + e8 + j] = v > 0.f ? v : 0.f;
    }
  }
}

// ---------------- K2: a = relu(embed @ Wa1^T + ba1) @ Wa2^T + ba2, layout [s*32+b][3] ----------------
__global__ __launch_bounds__(256) void k_attn(
    const float* __restrict__ emb, const float* __restrict__ Wa1,
    const float* __restrict__ ba1, const float* __restrict__ Wa2,
    const float* __restrict__ ba2, float* __restrict__ aw)
{
  __shared__ float sE[2 * 128];
  __shared__ float sH[2 * 128];
  const int tid = threadIdx.x;
  const int rs0 = blockIdx.x * 2;
  sE[tid] = emb[(size_t)rs0 * 128 + tid];
  __syncthreads();
  const int half = tid >> 7, j = tid & 127;
  const float* w = Wa1 + j * 128;
  const float* e = sE + half * 128;
  float a0 = 0.f, a1 = 0.f, a2 = 0.f, a3 = 0.f;
  for (int k = 0; k < 128; k += 16) DOT16(w, e, k);
  float h = (a0 + a1) + (a2 + a3) + ba1[j];
  sH[half * 128 + j] = h > 0.f ? h : 0.f;
  __syncthreads();
  if (tid < 6) {
    int hh = tid / 3, l = tid % 3;
    const float* w2 = Wa2 + l * 128;
    const float* hv = sH + hh * 128;
    float s = 0.f;
    for (int k = 0; k < 128; ++k) s = fmaf(w2[k], hv[k], s);
    aw[(size_t)(rs0 + hh) * 3 + l] = s + ba2[l];
  }
}

// ---------------- K2b: softmax over time (axis s) per (b, l), in-place ----------------
__global__ __launch_bounds__(256) void k_softmax(float* __restrict__ aw)
{
  __shared__ float red[256];
  const int b = blockIdx.x / 3, l = blockIdx.x % 3;
  const int tid = threadIdx.x;
  float v[4];
#pragma unroll
  for (int i = 0; i < 4; ++i) {
    int s = tid + i * 256;
    v[i] = aw[(size_t)(s * 32 + b) * 3 + l];
  }
  float mx = fmaxf(fmaxf(v[0], v[1]), fmaxf(v[2], v[3]));
  red[tid] = mx;
  __syncthreads();
  for (int off = 128; off > 0; off >>= 1) {
    if (tid < off) red[tid] = fmaxf(red[tid], red[tid + off]);
    __syncthreads();
  }
  mx = red[0];
  __syncthreads();
  float sm = 0.f;
#pragma unroll
  for (int i = 0; i < 4; ++i) sm += __expf(v[i] - mx);
  red[tid] = sm;
  __syncthreads();
  for (int off = 128; off > 0; off >>= 1) {
    if (tid < off) red[tid] += red[tid + off];
    __syncthreads();
  }
  float inv = 1.f / red[0];
#pragma unroll
  for (int i = 0; i < 4; ++i) {
    int s = tid + i * 256;
    aw[(size_t)(s * 32 + b) * 3 + l] = __expf(v[i] - mx) * inv;
  }
}

// ------- K_prep: repack Wih_d (516-stride) + bias sums + Wo1 transpose -------
__global__ __launch_bounds__(256) void k_prep(
    const float* __restrict__ Wih_d, const float* __restrict__ Wo1,
    const float* __restrict__ bih_e, const float* __restrict__ bhh_e,
    const float* __restrict__ bih_d, const float* __restrict__ bhh_d,
    float* __restrict__ wdpack, float* __restrict__ wo1t,
    float* __restrict__ bsum_e, float* __restrict__ bsum_d)
{
  const int row = blockIdx.x;           // 2048 rows
  const int tid = threadIdx.x;
  for (int q = tid; q < 516; q += 256) {
    float v = 0.f;
    if (q < 512)      v = Wih_d[(size_t)row * 513 + 1 + q];   // ctx part
    else if (q == 512) v = Wih_d[(size_t)row * 513];          // p coefficient
    wdpack[(size_t)row * 516 + q] = v;
  }
  if (row < 512) {   // wo1t[d][e] = Wo1[e][d]
    for (int e = tid; e < 512; e += 256)
      wo1t[(size_t)row * 512 + e] = Wo1[(size_t)e * 512 + row];
  }
  if (tid == 0) {
    bsum_e[row] = bih_e[row] + bhh_e[row];
    bsum_d[row] = bih_d[row] + bhh_d[row];
  }
}

// ---------------- K_init: initial states + barrier zero ----------------
__global__ __launch_bounds__(256) void k_init(
    const float* __restrict__ eh0, const float* __restrict__ dh0,
    float* __restrict__ heb, float* __restrict__ hdb,
    unsigned* __restrict__ bar)
{
  const int i = blockIdx.x * 256 + threadIdx.x;   // 32768 threads
  if (i < 16384) {
    int k = i & 511;
    heb[16384 + i] = eh0[k];   // heb slot 1 holds h_e(-1)  (staged at round 0)
    hdb[16384 + i] = dh0[k];   // hdb slot 1 holds h_d(-1)  (staged at round 1)
  }
  if (i < 1024) bar[i] = 0u;
}

// ---------------- group barrier: 8 wgs of one batch-pair group, UC atomics ----------------
__device__ __forceinline__ void groupbar(unsigned* cnt, unsigned* flag, unsigned gen)
{
  __builtin_amdgcn_s_waitcnt(0);     // drain this wave's stores/atomics
  __syncthreads();
  if (threadIdx.x == 0) {
    asm volatile("" ::: "memory");
    unsigned old = AGADD(cnt, 1u);
    if (old == (gen << 3) - 1u)          // last of this group's 8 wgs
      AGST(flag, gen);
    while (AGLD(flag) < gen)
      __builtin_amdgcn_s_sleep(1);
    asm volatile("" ::: "memory");
  }
  __syncthreads();
}

// ---------------- K_persist: 16 groups x 8 slices, 2 batches/wg, 1 barrier/step ----------------
// wg = (gp = blockIdx>>3, r8 = blockIdx&7), 512 threads. Group gp owns batches {2gp, 2gp+1};
// slice r8 owns h-dims [r8*64,(r8+1)*64) of BOTH LSTMs + the same rows of Wo1 (via wo1t).
// r8 == blockIdx%8 pins each slice to one XCD -> its ~1.8 MB of weight rows stays
// L2-resident, read by 16 wgs (2 batches each): half the L2 weight traffic of 1-batch wgs.
// Round i (all cross-wg deps strictly prior-round; ONE 8-wg barrier, NO spins, NO atomics):
//   enc step i       from h_e(i-1), emb(i)           -> publish h_e(i), ctx(i)
//   p(i-2)           from qpart(i-2) chunks (written round i-1), wg-local sum + finish
//   dec step i-1     from ctx(i-1), h_d(i-2), p(i-2) -> publish h_d(i-1)
//   qpart(i-1)       = wo1t[slice]^T . h_d_slice(i-1) (fresh, via LDS) -> private UC stores
__global__ __launch_bounds__(512) void k_persist(
    const float* __restrict__ emb, const float* __restrict__ aw,
    const int* __restrict__ lens,
    const float* __restrict__ Wih_e, const float* __restrict__ Whh_e,
    const float* __restrict__ Whh_d, const float* __restrict__ wdpack,
    const float* __restrict__ bsum_e, const float* __restrict__ bsum_d,
    const float* __restrict__ ec0, const float* __restrict__ dc0,
    const float* __restrict__ wo1t, const float* __restrict__ bo1,
    const float* __restrict__ Wo2, const float* __restrict__ bo2,
    const float* __restrict__ maskp,
    float* __restrict__ heb, float* __restrict__ hdb,
    float* __restrict__ ctxb, float* __restrict__ qpart,
    float* __restrict__ out, unsigned* __restrict__ bar)
{
  __shared__ float sHe[2 * 516];   // h_e(i-1) per batch (516-stride padding)
  __shared__ float sCtx[2 * 516];  // ctx(i-1)
  __shared__ float sHd[2 * 516];   // h_d(i-2)
  __shared__ float sEmb[2 * 132];  // emb(i)
  __shared__ float sGe[512], sGd[512];
  __shared__ float sHdNew[128];    // fresh h_d(i-1) slice: [d*2 + bt]
  __shared__ float sRed[8];        // per-wave partial of p (waves 0-3: bt0, 4-7: bt1)

  const int tid = threadIdx.x;
  const int gp = blockIdx.x >> 3;       // batch-pair group 0..15
  const int r8 = blockIdx.x & 7;        // slice 0..7 (== XCD if round-robin)
  const int b0 = gp << 1;
  const int rr = tid >> 1;              // gate-row within slice 0..255
  const int bt = tid & 1;               // batch within pair
  const int grow = ((rr >> 6) << 9) + (r8 << 6) + (rr & 63);

  unsigned* cnt  = bar + gp * 32;
  unsigned* flag = bar + gp * 32 + 16;

  const float be_row = bsum_e[grow];
  const float bd_row = bsum_d[grow];
  const float bo2v = bo2[0];

  // cell state: tid < 128 owns (dim = r8*64 + tid>>1, batch = b0 + (tid&1))
  float c_e = 0.f, c_d = 0.f, hm1 = 0.f, hm2 = 0.f;
  float pc0 = 0.f, pc1 = 0.f, pc2 = 0.f, pc3 = 0.f;
  int len_b = 0;
  if (tid < 128) {
    int dim = (r8 << 6) + (tid >> 1);
    c_e = ec0[dim];
    c_d = dc0[dim];
    len_b = lens[b0 + (tid & 1)];
    pc0 = wdpack[(size_t)(0 * 512 + dim) * 516 + 512];
    pc1 = wdpack[(size_t)(1 * 512 + dim) * 516 + 512];
    pc2 = wdpack[(size_t)(2 * 512 + dim) * 516 + 512];
    pc3 = wdpack[(size_t)(3 * 512 + dim) * 516 + 512];
  }

  const float* whe = Whh_e + (size_t)grow * 512;
  const float* wie = Wih_e + (size_t)grow * 128;
  const float* whd = Whh_d + (size_t)grow * 512;
  const float* wdc = wdpack + (size_t)grow * 516;
  const float* hX  = sHe  + bt * 516;
  const float* hC  = sCtx + bt * 516;
  const float* hD  = sHd  + bt * 516;
  const float* hE  = sEmb + bt * 132;

  for (int i = 0; i < 1026; ++i) {
    const bool doEnc = (i < 1024);
    const bool doDec = (i >= 1) && (i <= 1024);
    const bool doP   = (i >= 2);

    // ---- stage prior-round state (all barrier-covered) ----
    {
      const float* hep = heb  + (size_t)((i + 1) & 1) * 16384 + (size_t)b0 * 512;  // h_e(i-1)
      const float* cpp = ctxb + (size_t)((i + 1) & 1) * 16384 + (size_t)b0 * 512;  // ctx(i-1)
      const float* hdp = hdb  + (size_t)(i & 1) * 16384 + (size_t)b0 * 512;        // h_d(i-2)
      float vHe[2], vC[2], vHd[2];
#pragma unroll
      for (int j = 0; j < 2; ++j) {
        int idx = tid + j * 512;
        vHe[j] = AGLD(hep + idx);
        vC[j]  = AGLD(cpp + idx);
        vHd[j] = AGLD(hdp + idx);
      }
#pragma unroll
      for (int j = 0; j < 2; ++j) {
        int idx = tid + j * 512, bj = idx >> 9, kk = idx & 511;
        sHe [bj * 516 + kk] = vHe[j];
        sCtx[bj * 516 + kk] = vC[j];
        sHd [bj * 516 + kk] = vHd[j];
      }
      if (doEnc && tid < 64) {
        int btl = tid >> 5, q = (tid & 31) << 2;
        float4 ev = *(const float4*)(emb + (size_t)(i * 32 + b0 + btl) * 128 + q);
        *(float4*)(sEmb + btl * 132 + q) = ev;
      }
    }

    // ---- q chunk-sum for p(i-2): 8 private partials, plain loads (no atomics) ----
    float q0 = 0.f, q1 = 0.f;
    if (doP) {
      const int eb = tid >> 8;          // batch
      const int e  = tid & 255;
      const float* qp = qpart + (size_t)(i & 1) * 131072
                      + (size_t)(b0 + eb) * 4096 + e;      // slot (i-2)&1
#pragma unroll
      for (int rch = 0; rch < 8; ++rch) {
        q0 += AGLD(qp + rch * 512);
        q1 += AGLD(qp + rch * 512 + 256);
      }
    }
    __syncthreads();

    // ---- enc gates: full 640-dot per (row, batch) thread; lane pairs share weight row ----
    if (doEnc) {
      float a0 = 0.f, a1 = 0.f, a2 = 0.f, a3 = 0.f;
#pragma unroll 4
      for (int k = 0; k < 512; k += 16) DOT16(whe, hX, k);
#pragma unroll
      for (int k = 0; k < 128; k += 16) DOT16(wie, hE, k);
      sGe[tid] = (a0 + a1) + (a2 + a3) + be_row;
    }

    // ---- dec gates (p-independent): ctx(i-1) + h_d(i-2), full 1024-dot ----
    if (doDec) {
      float a0 = 0.f, a1 = 0.f, a2 = 0.f, a3 = 0.f;
#pragma unroll 2
      for (int k = 0; k < 512; k += 16) { DOT16(whd, hD, k); DOT16(wdc, hC, k); }
      sGd[tid] = (a0 + a1) + (a2 + a3) + bd_row;
    }

    // ---- finish p(i-2) partials: relu(q + bo1) . Wo2, wave reduce ----
    {
      float ps = 0.f;
      if (doP) {
        const int e = tid & 255;
        float t0 = q0 + bo1[e];
        float t1 = q1 + bo1[e + 256];
        ps = (t0 > 0.f ? t0 : 0.f) * Wo2[e] + (t1 > 0.f ? t1 : 0.f) * Wo2[e + 256];
      }
      ps += __shfl_down(ps, 32);
      ps += __shfl_down(ps, 16);
      ps += __shfl_down(ps, 8);
      ps += __shfl_down(ps, 4);
      ps += __shfl_down(ps, 2);
      ps += __shfl_down(ps, 1);
      if ((tid & 63) == 0) sRed[tid >> 6] = ps;
    }
    __syncthreads();

    // ---- cells + out write (tid < 128) ----
    if (tid < 128) {
      const int d = tid >> 1, btc = tid & 1;
      const int dim = (r8 << 6) + d;
      const int gb = b0 + btc;
      if (doEnc) {
        float gi = sGe[tid], gf = sGe[128 + tid], gg = sGe[256 + tid], go = sGe[384 + tid];
        c_e = sigm(gf) * c_e + sigm(gi) * tanh_(gg);
        float h = sigm(go) * tanh_(c_e);
        AGST(&heb[(size_t)(i & 1) * 16384 + (size_t)gb * 512 + dim], h);
        float hmv = (i < len_b) ? h : 0.f;
        const float* at = aw + (size_t)(i * 32 + gb) * 3;
        float ctx = at[0] * hmv + at[1] * hm1 + at[2] * hm2;
        hm2 = hm1; hm1 = hmv;
        AGST(&ctxb[(size_t)(i & 1) * 16384 + (size_t)gb * 512 + dim], ctx);
      }
      float p = 0.f;
      if (doP)
        p = sRed[(btc << 2)] + sRed[(btc << 2) + 1] + sRed[(btc << 2) + 2]
          + sRed[(btc << 2) + 3] + bo2v;
      if (doDec) {
        float gi = sGd[tid]       + pc0 * p;
        float gf = sGd[128 + tid] + pc1 * p;
        float gg = sGd[256 + tid] + pc2 * p;
        float go = sGd[384 + tid] + pc3 * p;
        c_d = sigm(gf) * c_d + sigm(gi) * tanh_(gg);
        float h = sigm(go) * tanh_(c_d);
        AGST(&hdb[(size_t)((i + 1) & 1) * 16384 + (size_t)gb * 512 + dim], h);  // slot (i-1)&1
        sHdNew[tid] = h;
      }
      if (doP && r8 == 0 && d == 0)     // designated writer: out[b][i-2]
        AGST(&out[(size_t)gb * 1024 + (i - 2)], p);
    }
    __syncthreads();

    // ---- qpart(i-1) = wo1t[slice]^T . h_d_slice(i-1), private region, plain stores ----
    if (doDec) {
      const int eb = tid >> 8, e = tid & 255;
      float a0 = 0.f, a1 = 0.f;
      const float* w = wo1t + (size_t)(r8 << 6) * 512 + e;
#pragma unroll 8
      for (int d = 0; d < 64; ++d) {
        float h = sHdNew[(d << 1) + eb];
        a0 = fmaf(w[(size_t)d * 512], h, a0);
        a1 = fmaf(w[(size_t)d * 512 + 256], h, a1);
      }
      float* qdst = qpart + (size_t)((i + 1) & 1) * 131072      // slot (i-1)&1
                  + (size_t)(b0 + eb) * 4096 + (r8 << 9) + e;
      AGST(qdst, a0);
      AGST(qdst + 256, a1);
    }

    groupbar(cnt, flag, (unsigned)(i + 1));
  }

  // ---- mask own chunk: 256 outputs per wg, all in-group (barrier-covered) ----
  if (tid < 256) {
    int idx = (gp << 11) + (r8 << 8) + tid;
    float v = AGLD(&out[idx]);
    out[idx] = v * maskp[idx];
  }
}

extern "C" void kernel_launch(void* const* d_in, const int* in_sizes, int n_in,
                              void* d_out, int out_size, void* d_ws, size_t ws_size,
                              hipStream_t stream)
{
  const float* inp   = (const float*)d_in[0];
  const float* maskp = (const float*)d_in[1];
  const int*   lens  = (const int*)d_in[2];
  const float* We    = (const float*)d_in[3];
  const float* be    = (const float*)d_in[4];
  const float* Wa1   = (const float*)d_in[5];
  const float* ba1   = (const float*)d_in[6];
  const float* Wa2   = (const float*)d_in[7];
  const float* ba2   = (const float*)d_in[8];
  const float* Wih_e = (const float*)d_in[9];
  const float* Whh_e = (const float*)d_in[10];
  const float* bih_e = (const float*)d_in[11];
  const float* bhh_e = (const float*)d_in[12];
  const float* eh0   = (const float*)d_in[13];
  const float* ec0   = (const float*)d_in[14];
  const float* Wih_d = (const float*)d_in[15];
  const float* Whh_d = (const float*)d_in[16];
  const float* bih_d = (const float*)d_in[17];
  const float* bhh_d = (const float*)d_in[18];
  const float* dh0   = (const float*)d_in[19];
  const float* dc0   = (const float*)d_in[20];
  const float* Wo1   = (const float*)d_in[21];
  const float* bo1   = (const float*)d_in[22];
  const float* Wo2   = (const float*)d_in[23];
  const float* bo2   = (const float*)d_in[24];

  float* ws     = (float*)d_ws;
  float* emb    = ws;                     // 4,194,304
  float* aw     = emb + 4194304;          //    98,304
  float* heb    = aw + 98304;             //    32,768 (2 slots)
  float* hdb    = heb + 32768;            //    32,768 (2 slots)
  float* ctxb   = hdb + 32768;            //    32,768 (2 slots)
  float* qpart  = ctxb + 32768;           //   262,144 (2 slots x 32 b x 8 r x 512)
  float* wdpack = qpart + 262144;         // 1,056,768 (2048 x 516)
  float* wo1t   = wdpack + 1056768;       //   262,144 (512 x 512, transposed Wo1)
  float* bsum_e = wo1t + 262144;          //     2,048
  float* bsum_d = bsum_e + 2048;          //     2,048
  unsigned* bar = (unsigned*)(bsum_d + 2048);  // 1,024 (16 groups x 32)
  float* outf = (float*)d_out;

  k_embed<<<512, 256, 0, stream>>>(inp, We, be, emb);
  k_attn<<<16384, 256, 0, stream>>>(emb, Wa1, ba1, Wa2, ba2, aw);
  k_softmax<<<96, 256, 0, stream>>>(aw);
  k_prep<<<2048, 256, 0, stream>>>(Wih_d, Wo1, bih_e, bhh_e, bih_d, bhh_d,
                                   wdpack, wo1t, bsum_e, bsum_d);
  k_init<<<128, 256, 0, stream>>>(eh0, dh0, heb, hdb, bar);

  k_persist<<<128, 512, 0, stream>>>(
      emb, aw, lens,
      Wih_e, Whh_e, Whh_d, wdpack, bsum_e, bsum_d,
      ec0, dc0, wo1t, bo1, Wo2, bo2, maskp,
      heb, hdb, ctxb, qpart, outf, bar);
}

// Round 7
// 30166.779 us; speedup vs baseline: 4.2300x; 1.5647x over previous
//
#include <hip/hip_runtime.h>
#include <cstddef>

__device__ __forceinline__ float sigm(float x) { return 1.f / (1.f + __expf(-x)); }
__device__ __forceinline__ float tanh_(float x) { return 1.f - 2.f / (__expf(2.f * x) + 1.f); }

#define AGLD(p)    __hip_atomic_load((p),  __ATOMIC_RELAXED, __HIP_MEMORY_SCOPE_AGENT)
#define AGST(p, v) __hip_atomic_store((p), (v), __ATOMIC_RELAXED, __HIP_MEMORY_SCOPE_AGENT)
#define AGADD(p,v) __hip_atomic_fetch_add((p), (v), __ATOMIC_RELAXED, __HIP_MEMORY_SCOPE_AGENT)

// 16-wide fp32 dot block: accumulates into a0..a3 (declared by caller)
#define DOT16(wp, hp, kk) do { \
    float4 w0_ = *(const float4*)((wp) + (kk));      float4 x0_ = *(const float4*)((hp) + (kk)); \
    float4 w1_ = *(const float4*)((wp) + (kk) + 4);  float4 x1_ = *(const float4*)((hp) + (kk) + 4); \
    float4 w2_ = *(const float4*)((wp) + (kk) + 8);  float4 x2_ = *(const float4*)((hp) + (kk) + 8); \
    float4 w3_ = *(const float4*)((wp) + (kk) + 12); float4 x3_ = *(const float4*)((hp) + (kk) + 12); \
    a0 = fmaf(w0_.x, x0_.x, a0); a0 = fmaf(w0_.y, x0_.y, a0); a0 = fmaf(w0_.z, x0_.z, a0); a0 = fmaf(w0_.w, x0_.w, a0); \
    a1 = fmaf(w1_.x, x1_.x, a1); a1 = fmaf(w1_.y, x1_.y, a1); a1 = fmaf(w1_.z, x1_.z, a1); a1 = fmaf(w1_.w, x1_.w, a1); \
    a2 = fmaf(w2_.x, x2_.x, a2); a2 = fmaf(w2_.y, x2_.y, a2); a2 = fmaf(w2_.z, x2_.z, a2); a2 = fmaf(w2_.w, x2_.w, a2); \
    a3 = fmaf(w3_.x, x3_.x, a3); a3 = fmaf(w3_.y, x3_.y, a3); a3 = fmaf(w3_.z, x3_.z, a3); a3 = fmaf(w3_.w, x3_.w, a3); \
  } while (0)

// ---------------- K1: embed = relu(inputs @ W_e^T + b_e), layout [s][b][e] ----------------
__global__ __launch_bounds__(256) void k_embed(
    const float* __restrict__ inp, const float* __restrict__ We,
    const float* __restrict__ be, float* __restrict__ emb)
{
  __shared__ float sA[32 * 68];
  __shared__ float sW[32 * 132];
  const int tid = threadIdx.x;
  const int b  = blockIdx.x >> 4;
  const int s0 = (blockIdx.x & 15) << 6;
  float acc[4][8];
#pragma unroll
  for (int i = 0; i < 4; ++i)
#pragma unroll
    for (int j = 0; j < 8; ++j) acc[i][j] = 0.f;
  const int m4 = (tid & 15) << 2;
  const int e8 = (tid >> 4) << 3;
  const float* Ab = inp + ((size_t)(b << 10) + s0) * 1024;
  const int ms = tid >> 2, kq = tid & 3;
  const int es = tid >> 1, kq2 = tid & 1;
  for (int k0 = 0; k0 < 1024; k0 += 32) {
    __syncthreads();
    {
      const float* src = Ab + (size_t)ms * 1024 + k0 + (kq << 3);
      float4 v0 = *(const float4*)(src);
      float4 v1 = *(const float4*)(src + 4);
      int kb = kq << 3;
      sA[(kb+0)*68+ms] = v0.x; sA[(kb+1)*68+ms] = v0.y;
      sA[(kb+2)*68+ms] = v0.z; sA[(kb+3)*68+ms] = v0.w;
      sA[(kb+4)*68+ms] = v1.x; sA[(kb+5)*68+ms] = v1.y;
      sA[(kb+6)*68+ms] = v1.z; sA[(kb+7)*68+ms] = v1.w;
    }
    {
      const float* src = We + (size_t)es * 1024 + k0 + (kq2 << 4);
#pragma unroll
      for (int q = 0; q < 4; ++q) {
        float4 v = *(const float4*)(src + (q << 2));
        int kb = (kq2 << 4) + (q << 2);
        sW[(kb+0)*132+es] = v.x; sW[(kb+1)*132+es] = v.y;
        sW[(kb+2)*132+es] = v.z; sW[(kb+3)*132+es] = v.w;
      }
    }
    __syncthreads();
#pragma unroll 4
    for (int kk = 0; kk < 32; ++kk) {
      float4 a4 = *(const float4*)&sA[kk*68 + m4];
      float4 b0 = *(const float4*)&sW[kk*132 + e8];
      float4 b1 = *(const float4*)&sW[kk*132 + e8 + 4];
      float av[4] = {a4.x, a4.y, a4.z, a4.w};
      float bv[8] = {b0.x, b0.y, b0.z, b0.w, b1.x, b1.y, b1.z, b1.w};
#pragma unroll
      for (int i = 0; i < 4; ++i)
#pragma unroll
        for (int j = 0; j < 8; ++j) acc[i][j] = fmaf(av[i], bv[j], acc[i][j]);
    }
  }
#pragma unroll
  for (int i = 0; i < 4; ++i) {
    int s = s0 + m4 + i;
#pragma unroll
    for (int j = 0; j < 8; ++j) {
      float v = acc[i][j] + be[e8 + j];
      emb[((size_t)(s << 5) + b) * 128 + e8 + j] = v > 0.f ? v : 0.f;
    }
  }
}

// ---------------- K2: a = relu(embed @ Wa1^T + ba1) @ Wa2^T + ba2, layout [s*32+b][3] ----------------
__global__ __launch_bounds__(256) void k_attn(
    const float* __restrict__ emb, const float* __restrict__ Wa1,
    const float* __restrict__ ba1, const float* __restrict__ Wa2,
    const float* __restrict__ ba2, float* __restrict__ aw)
{
  __shared__ float sE[2 * 128];
  __shared__ float sH[2 * 128];
  const int tid = threadIdx.x;
  const int rs0 = blockIdx.x * 2;
  sE[tid] = emb[(size_t)rs0 * 128 + tid];
  __syncthreads();
  const int half = tid >> 7, j = tid & 127;
  const float* w = Wa1 + j * 128;
  const float* e = sE + half * 128;
  float a0 = 0.f, a1 = 0.f, a2 = 0.f, a3 = 0.f;
  for (int k = 0; k < 128; k += 16) DOT16(w, e, k);
  float h = (a0 + a1) + (a2 + a3) + ba1[j];
  sH[half * 128 + j] = h > 0.f ? h : 0.f;
  __syncthreads();
  if (tid < 6) {
    int hh = tid / 3, l = tid % 3;
    const float* w2 = Wa2 + l * 128;
    const float* hv = sH + hh * 128;
    float s = 0.f;
    for (int k = 0; k < 128; ++k) s = fmaf(w2[k], hv[k], s);
    aw[(size_t)(rs0 + hh) * 3 + l] = s + ba2[l];
  }
}

// ---------------- K2b: softmax over time (axis s) per (b, l), in-place ----------------
__global__ __launch_bounds__(256) void k_softmax(float* __restrict__ aw)
{
  __shared__ float red[256];
  const int b = blockIdx.x / 3, l = blockIdx.x % 3;
  const int tid = threadIdx.x;
  float v[4];
#pragma unroll
  for (int i = 0; i < 4; ++i) {
    int s = tid + i * 256;
    v[i] = aw[(size_t)(s * 32 + b) * 3 + l];
  }
  float mx = fmaxf(fmaxf(v[0], v[1]), fmaxf(v[2], v[3]));
  red[tid] = mx;
  __syncthreads();
  for (int off = 128; off > 0; off >>= 1) {
    if (tid < off) red[tid] = fmaxf(red[tid], red[tid + off]);
    __syncthreads();
  }
  mx = red[0];
  __syncthreads();
  float sm = 0.f;
#pragma unroll
  for (int i = 0; i < 4; ++i) sm += __expf(v[i] - mx);
  red[tid] = sm;
  __syncthreads();
  for (int off = 128; off > 0; off >>= 1) {
    if (tid < off) red[tid] += red[tid + off];
    __syncthreads();
  }
  float inv = 1.f / red[0];
#pragma unroll
  for (int i = 0; i < 4; ++i) {
    int s = tid + i * 256;
    aw[(size_t)(s * 32 + b) * 3 + l] = __expf(v[i] - mx) * inv;
  }
}

// ------- K_prep: repack Wih_d (516-stride) + bias sums + Wo1 transpose -------
__global__ __launch_bounds__(256) void k_prep(
    const float* __restrict__ Wih_d, const float* __restrict__ Wo1,
    const float* __restrict__ bih_e, const float* __restrict__ bhh_e,
    const float* __restrict__ bih_d, const float* __restrict__ bhh_d,
    float* __restrict__ wdpack, float* __restrict__ wo1t,
    float* __restrict__ bsum_e, float* __restrict__ bsum_d)
{
  const int row = blockIdx.x;           // 2048 rows
  const int tid = threadIdx.x;
  for (int q = tid; q < 516; q += 256) {
    float v = 0.f;
    if (q < 512)      v = Wih_d[(size_t)row * 513 + 1 + q];   // ctx part
    else if (q == 512) v = Wih_d[(size_t)row * 513];          // p coefficient
    wdpack[(size_t)row * 516 + q] = v;
  }
  if (row < 512) {   // wo1t[d][e] = Wo1[e][d]
    for (int e = tid; e < 512; e += 256)
      wo1t[(size_t)row * 512 + e] = Wo1[(size_t)e * 512 + row];
  }
  if (tid == 0) {
    bsum_e[row] = bih_e[row] + bhh_e[row];
    bsum_d[row] = bih_d[row] + bhh_d[row];
  }
}

// ---------------- K_init: initial states + barrier zero ----------------
__global__ __launch_bounds__(256) void k_init(
    const float* __restrict__ eh0, const float* __restrict__ dh0,
    float* __restrict__ heb, float* __restrict__ hdb,
    unsigned* __restrict__ bar)
{
  const int i = blockIdx.x * 256 + threadIdx.x;   // 32768 threads
  if (i < 16384) {
    int k = i & 511;
    heb[16384 + i] = eh0[k];   // heb slot 1 holds h_e(-1)  (staged at round 0)
    hdb[16384 + i] = dh0[k];   // hdb slot 1 holds h_d(-1)  (staged at round 1)
  }
  if (i < 1024) bar[i] = 0u;
}

// ------- per-batch barrier: 8 wgs, UC atomics only (r0-proven structure) -------
__device__ __forceinline__ void batchbar(unsigned* cnt, unsigned* flag, unsigned gen)
{
  __builtin_amdgcn_s_waitcnt(0);     // drain this wave's stores/atomics
  __syncthreads();
  if (threadIdx.x == 0) {
    asm volatile("" ::: "memory");
    unsigned old = AGADD(cnt, 1u);
    if (old == (gen << 3) - 1u)      // last of this batch's 8 wgs
      AGST(flag, gen);
    while (AGLD(flag) < gen)
      __builtin_amdgcn_s_sleep(1);
    asm volatile("" ::: "memory");
  }
  __syncthreads();
}

// ---------------- K_persist: 32 batches x 8 slices, ONE barrier per timestep ----------------
// wg = (b = blockIdx>>3, s = blockIdx&7), 256 threads — r0's proven microstructure.
// Skewed rounds (all cross-wg deps strictly prior-round; no spins, no atomics):
//   round i: enc(i)    from h_e(i-1)[slot (i+1)&1], emb(i)      -> h_e(i),ctx(i) [slot i&1]
//            p(i-2)    from qpart slot i&1 (written round i-1), redundant 8-wg fan-in
//            dec(i-1)  from ctx(i-1)[slot (i+1)&1], h_d(i-2)[slot i&1], p(i-2)
//                                                               -> h_d(i-1) [slot (i+1)&1]
//            qpart(i-1)= wo1t[slice]^T . h_d_slice(i-1) (fresh via LDS) -> slot (i+1)&1
__global__ __launch_bounds__(256) void k_persist(
    const float* __restrict__ emb, const float* __restrict__ aw,
    const int* __restrict__ lens,
    const float* __restrict__ Wih_e, const float* __restrict__ Whh_e,
    const float* __restrict__ Whh_d, const float* __restrict__ wdpack,
    const float* __restrict__ bsum_e, const float* __restrict__ bsum_d,
    const float* __restrict__ ec0, const float* __restrict__ dc0,
    const float* __restrict__ wo1t, const float* __restrict__ bo1,
    const float* __restrict__ Wo2, const float* __restrict__ bo2,
    const float* __restrict__ maskp,
    float* __restrict__ heb, float* __restrict__ hdb,
    float* __restrict__ ctxb, float* __restrict__ qpart,
    float* __restrict__ out, unsigned* __restrict__ bar)
{
  __shared__ float sHe[512], sCtx[512], sHd[512], sEmb[128];
  __shared__ float sGe[256], sGd[256];
  __shared__ float sHdNew[64];
  __shared__ float sRed[4];

  const int tid = threadIdx.x;
  const int b = blockIdx.x >> 3, s = blockIdx.x & 7;
  const int lane = tid & 63, w = tid >> 6;
  const int r8 = lane >> 3, kg = lane & 7;
  unsigned* cnt  = bar + b * 32;
  unsigned* flag = bar + b * 32 + 16;

  const float bo2v = bo2[0];

  // cell-state registers (tid < 64 owns h-dim s*64+tid)
  float c_e = 0.f, c_d = 0.f, hm1 = 0.f, hm2 = 0.f;
  float pc0 = 0.f, pc1 = 0.f, pc2 = 0.f, pc3 = 0.f;
  int len_b = lens[b];
  if (tid < 64) {
    int dim = (s << 6) + tid;
    c_e = ec0[dim];
    c_d = dc0[dim];
    pc0 = wdpack[(size_t)(0 * 512 + dim) * 516 + 512];
    pc1 = wdpack[(size_t)(1 * 512 + dim) * 516 + 512];
    pc2 = wdpack[(size_t)(2 * 512 + dim) * 516 + 512];
    pc3 = wdpack[(size_t)(3 * 512 + dim) * 516 + 512];
  }

  for (int i = 0; i < 1026; ++i) {
    const bool doEnc = (i < 1024);
    const bool doDec = (i >= 1) && (i <= 1024);
    const bool doP   = (i >= 2);

    // ---- stage prior-round state (UC) + emb (cached) + qpart fan-in (UC) ----
    float q0 = 0.f, q1 = 0.f;
    {
      const float* hep = heb  + (size_t)((i + 1) & 1) * 16384 + b * 512;  // h_e(i-1)
      const float* cpp = ctxb + (size_t)((i + 1) & 1) * 16384 + b * 512;  // ctx(i-1)
      const float* hdp = hdb  + (size_t)(i & 1) * 16384 + b * 512;        // h_d(i-2)
      float vHe0 = AGLD(hep + tid), vHe1 = AGLD(hep + tid + 256);
      float vC0  = AGLD(cpp + tid), vC1  = AGLD(cpp + tid + 256);
      float vHd0 = AGLD(hdp + tid), vHd1 = AGLD(hdp + tid + 256);
      if (doP) {  // q[e] = sum_s' qpart[b][s'][e], e in {tid, tid+256}
        const float* qp = qpart + (size_t)(i & 1) * 131072 + (size_t)b * 4096 + tid;
#pragma unroll
        for (int sc = 0; sc < 8; ++sc) {
          q0 += AGLD(qp + sc * 512);
          q1 += AGLD(qp + sc * 512 + 256);
        }
      }
      sHe[tid] = vHe0;  sHe[tid + 256] = vHe1;
      sCtx[tid] = vC0;  sCtx[tid + 256] = vC1;
      sHd[tid] = vHd0;  sHd[tid + 256] = vHd1;
      if (doEnc && tid < 128) sEmb[tid] = emb[(size_t)(i * 32 + b) * 128 + tid];
    }
    __syncthreads();

    // ---- p(i-2) partial: relu(q + bo1) . Wo2, per-wave reduce ----
    {
      float ps = 0.f;
      if (doP) {
        float t0 = q0 + bo1[tid];
        float t1 = q1 + bo1[tid + 256];
        ps = (t0 > 0.f ? t0 : 0.f) * Wo2[tid] + (t1 > 0.f ? t1 : 0.f) * Wo2[tid + 256];
      }
      ps += __shfl_down(ps, 32);
      ps += __shfl_down(ps, 16);
      ps += __shfl_down(ps, 8);
      ps += __shfl_down(ps, 4);
      ps += __shfl_down(ps, 2);
      ps += __shfl_down(ps, 1);
      if (lane == 0) sRed[w] = ps;
    }

    // ---- enc gates: 256 rows, 8 passes of (4 waves x 8 rows x 8 k-groups) [r0 verbatim] ----
    if (doEnc) {
#pragma unroll 2
      for (int pass = 0; pass < 8; ++pass) {
        const int rho = pass * 32 + w * 8 + r8;
        const int grow = ((rho >> 6) << 9) + (s << 6) + (rho & 63);
        const float4* wr = (const float4*)(Whh_e + (size_t)grow * 512);
        const float4* hr = (const float4*)sHe;
        float a0 = 0.f, a1 = 0.f, a2 = 0.f, a3 = 0.f;
#pragma unroll
        for (int kc = 0; kc < 16; kc += 4) {
          float4 w0 = wr[(kc+0)*8+kg], h0 = hr[(kc+0)*8+kg];
          float4 w1 = wr[(kc+1)*8+kg], h1 = hr[(kc+1)*8+kg];
          float4 w2 = wr[(kc+2)*8+kg], h2 = hr[(kc+2)*8+kg];
          float4 w3 = wr[(kc+3)*8+kg], h3 = hr[(kc+3)*8+kg];
          a0 = fmaf(w0.x,h0.x,a0); a0 = fmaf(w0.y,h0.y,a0); a0 = fmaf(w0.z,h0.z,a0); a0 = fmaf(w0.w,h0.w,a0);
          a1 = fmaf(w1.x,h1.x,a1); a1 = fmaf(w1.y,h1.y,a1); a1 = fmaf(w1.z,h1.z,a1); a1 = fmaf(w1.w,h1.w,a1);
          a2 = fmaf(w2.x,h2.x,a2); a2 = fmaf(w2.y,h2.y,a2); a2 = fmaf(w2.z,h2.z,a2); a2 = fmaf(w2.w,h2.w,a2);
          a3 = fmaf(w3.x,h3.x,a3); a3 = fmaf(w3.y,h3.y,a3); a3 = fmaf(w3.z,h3.z,a3); a3 = fmaf(w3.w,h3.w,a3);
        }
        const float4* wx = (const float4*)(Wih_e + (size_t)grow * 128);
        const float4* xr = (const float4*)sEmb;
#pragma unroll
        for (int kc = 0; kc < 4; ++kc) {
          float4 wv = wx[kc*8+kg], xv = xr[kc*8+kg];
          a0 = fmaf(wv.x,xv.x,a0); a1 = fmaf(wv.y,xv.y,a1);
          a2 = fmaf(wv.z,xv.z,a2); a3 = fmaf(wv.w,xv.w,a3);
        }
        float p = (a0 + a1) + (a2 + a3);
        p += __shfl_down(p, 4);
        p += __shfl_down(p, 2);
        p += __shfl_down(p, 1);
        if (kg == 0) sGe[rho] = p + bsum_e[grow];
      }
    }

    // ---- dec gates (p-independent): 256 rows over ctx(i-1) + h_d(i-2) [r0 verbatim] ----
    if (doDec) {
#pragma unroll 2
      for (int pass = 0; pass < 8; ++pass) {
        const int rho = pass * 32 + w * 8 + r8;
        const int grow = ((rho >> 6) << 9) + (s << 6) + (rho & 63);
        const float4* wh = (const float4*)(Whh_d + (size_t)grow * 512);
        const float4* wc = (const float4*)(wdpack + (size_t)grow * 516);
        const float4* hr = (const float4*)sHd;
        const float4* cr = (const float4*)sCtx;
        float a0 = 0.f, a1 = 0.f, a2 = 0.f, a3 = 0.f;
#pragma unroll
        for (int kc = 0; kc < 16; kc += 2) {
          float4 w0 = wh[(kc+0)*8+kg], h0 = hr[(kc+0)*8+kg];
          float4 w1 = wh[(kc+1)*8+kg], h1 = hr[(kc+1)*8+kg];
          float4 v0 = wc[(kc+0)*8+kg], c0 = cr[(kc+0)*8+kg];
          float4 v1 = wc[(kc+1)*8+kg], c1 = cr[(kc+1)*8+kg];
          a0 = fmaf(w0.x,h0.x,a0); a0 = fmaf(w0.y,h0.y,a0); a0 = fmaf(w0.z,h0.z,a0); a0 = fmaf(w0.w,h0.w,a0);
          a1 = fmaf(w1.x,h1.x,a1); a1 = fmaf(w1.y,h1.y,a1); a1 = fmaf(w1.z,h1.z,a1); a1 = fmaf(w1.w,h1.w,a1);
          a2 = fmaf(v0.x,c0.x,a2); a2 = fmaf(v0.y,c0.y,a2); a2 = fmaf(v0.z,c0.z,a2); a2 = fmaf(v0.w,c0.w,a2);
          a3 = fmaf(v1.x,c1.x,a3); a3 = fmaf(v1.y,c1.y,a3); a3 = fmaf(v1.z,c1.z,a3); a3 = fmaf(v1.w,c1.w,a3);
        }
        float p = (a0 + a1) + (a2 + a3);
        p += __shfl_down(p, 4);
        p += __shfl_down(p, 2);
        p += __shfl_down(p, 1);
        if (kg == 0) sGd[rho] = p + bsum_d[grow];
      }
    }
    __syncthreads();

    // ---- cells (tid < 64): enc cell, p(i-2), dec cell; publish (UC) ----
    if (tid < 64) {
      const int dim = (s << 6) + tid;
      const int ci = b * 512 + dim;
      if (doEnc) {
        float gi = sGe[tid], gf = sGe[64 + tid], gg = sGe[128 + tid], go = sGe[192 + tid];
        c_e = sigm(gf) * c_e + sigm(gi) * tanh_(gg);
        float h = sigm(go) * tanh_(c_e);
        AGST(&heb[(size_t)(i & 1) * 16384 + ci], h);
        float hmv = (i < len_b) ? h : 0.f;
        const float* at = aw + (size_t)(i * 32 + b) * 3;
        float ctx = at[0] * hmv + at[1] * hm1 + at[2] * hm2;
        hm2 = hm1; hm1 = hmv;
        AGST(&ctxb[(size_t)(i & 1) * 16384 + ci], ctx);
      }
      float p = 0.f;
      if (doP) p = sRed[0] + sRed[1] + sRed[2] + sRed[3] + bo2v;
      if (doDec) {
        float gi = sGd[tid]       + pc0 * p;
        float gf = sGd[64 + tid]  + pc1 * p;
        float gg = sGd[128 + tid] + pc2 * p;
        float go = sGd[192 + tid] + pc3 * p;
        c_d = sigm(gf) * c_d + sigm(gi) * tanh_(gg);
        float h = sigm(go) * tanh_(c_d);
        AGST(&hdb[(size_t)((i + 1) & 1) * 16384 + ci], h);   // h_d(i-1) -> slot (i-1)&1
        sHdNew[tid] = h;
      }
      if (doP && s == 0 && tid == 0)
        AGST(&out[(size_t)b * 1024 + (i - 2)], p);
    }
    __syncthreads();

    // ---- qpart(i-1): wo1t slice^T . h_d_slice(i-1); coalesced L2 reads, UC stores ----
    if (doDec) {
      float a0 = 0.f, a1 = 0.f;
      const float* wv = wo1t + (size_t)(s << 6) * 512 + tid;
#pragma unroll 8
      for (int d = 0; d < 64; ++d) {
        float h = sHdNew[d];
        a0 = fmaf(wv[(size_t)d * 512], h, a0);
        a1 = fmaf(wv[(size_t)d * 512 + 256], h, a1);
      }
      float* qdst = qpart + (size_t)((i + 1) & 1) * 131072 + (size_t)b * 4096 + (s << 9) + tid;
      AGST(qdst, a0);
      AGST(qdst + 256, a1);
    }

    batchbar(cnt, flag, (unsigned)(i + 1));
  }

  // ---- mask own slice: out[b][s*128 .. s*128+128) ----
  if (tid < 128) {
    int idx = b * 1024 + (s << 7) + tid;
    float v = AGLD(&out[idx]);
    out[idx] = v * maskp[idx];
  }
}

extern "C" void kernel_launch(void* const* d_in, const int* in_sizes, int n_in,
                              void* d_out, int out_size, void* d_ws, size_t ws_size,
                              hipStream_t stream)
{
  const float* inp   = (const float*)d_in[0];
  const float* maskp = (const float*)d_in[1];
  const int*   lens  = (const int*)d_in[2];
  const float* We    = (const float*)d_in[3];
  const float* be    = (const float*)d_in[4];
  const float* Wa1   = (const float*)d_in[5];
  const float* ba1   = (const float*)d_in[6];
  const float* Wa2   = (const float*)d_in[7];
  const float* ba2   = (const float*)d_in[8];
  const float* Wih_e = (const float*)d_in[9];
  const float* Whh_e = (const float*)d_in[10];
  const float* bih_e = (const float*)d_in[11];
  const float* bhh_e = (const float*)d_in[12];
  const float* eh0   = (const float*)d_in[13];
  const float* ec0   = (const float*)d_in[14];
  const float* Wih_d = (const float*)d_in[15];
  const float* Whh_d = (const float*)d_in[16];
  const float* bih_d = (const float*)d_in[17];
  const float* bhh_d = (const float*)d_in[18];
  const float* dh0   = (const float*)d_in[19];
  const float* dc0   = (const float*)d_in[20];
  const float* Wo1   = (const float*)d_in[21];
  const float* bo1   = (const float*)d_in[22];
  const float* Wo2   = (const float*)d_in[23];
  const float* bo2   = (const float*)d_in[24];

  float* ws     = (float*)d_ws;
  float* emb    = ws;                     // 4,194,304
  float* aw     = emb + 4194304;          //    98,304
  float* heb    = aw + 98304;             //    32,768 (2 slots)
  float* hdb    = heb + 32768;            //    32,768 (2 slots)
  float* ctxb   = hdb + 32768;            //    32,768 (2 slots)
  float* qpart  = ctxb + 32768;           //   262,144 (2 slots x 32 b x 8 s x 512)
  float* wdpack = qpart + 262144;         // 1,056,768 (2048 x 516)
  float* wo1t   = wdpack + 1056768;       //   262,144 (512 x 512, transposed Wo1)
  float* bsum_e = wo1t + 262144;          //     2,048
  float* bsum_d = bsum_e + 2048;          //     2,048
  unsigned* bar = (unsigned*)(bsum_d + 2048);  // 1,024 (32 batches x 32)
  float* outf = (float*)d_out;

  k_embed<<<512, 256, 0, stream>>>(inp, We, be, emb);
  k_attn<<<16384, 256, 0, stream>>>(emb, Wa1, ba1, Wa2, ba2, aw);
  k_softmax<<<96, 256, 0, stream>>>(aw);
  k_prep<<<2048, 256, 0, stream>>>(Wih_d, Wo1, bih_e, bhh_e, bih_d, bhh_d,
                                   wdpack, wo1t, bsum_e, bsum_d);
  k_init<<<128, 256, 0, stream>>>(eh0, dh0, heb, hdb, bar);

  k_persist<<<256, 256, 0, stream>>>(
      emb, aw, lens,
      Wih_e, Whh_e, Whh_d, wdpack, bsum_e, bsum_d,
      ec0, dc0, wo1t, bo1, Wo2, bo2, maskp,
      heb, hdb, ctxb, qpart, outf, bar);
}